// Round 10
// baseline (1848.162 us; speedup 1.0000x reference)
//
#include <hip/hip_runtime.h>
#include <hip/hip_bf16.h>

// SwinMLP block, fp32 in/out, bf16 MFMA internals.
//   1) cvt_t: w1 -> w1t (bf16, NxK), w2 -> w2t (bf16, NxK)
//   2) fused_pre: LN1 + per-head 32x32 spatial mix + residual -> x2 (d_out)
//      + LN2(x2) -> y (bf16, ws)
//   3) gemmdr<512,2048,GELU>: z = gelu(y @ w1 + b1)
//   4) gemmdr<2048,512,RES>:  d_out = x2 + z @ w2 + b2
//
// R4-R9 finding: six schedule variants all pinned at 22-23% MfmaUtil, 21%
// occupancy (= 2 reg-bound waves/SIMD; acc128 AGPR + 116 VGPR). Lockstep
// block-wide barriers burst-serialize LDS pipe vs matrix pipe; no foreign
// wave exists to fill gaps. Bank-conflict counter invariant across layouts
// (inherent b128 replay). R10: REMOVE LDS/BARRIERS/WAITCNT from the K-loop
// entirely — fragments load global->VGPR with exact MFMA per-lane addressing
// (16-row gather; 64B lines fully consumed by kg-lanes; panels L2/L1-hot
// under T1 swizzle). Zero sync => waves drift, compiler pipelines loads
// across MFMA clusters. LDS used only for the coalesced epilogue bounce.

typedef __bf16 bf16x8 __attribute__((ext_vector_type(8)));
typedef float f32x4 __attribute__((ext_vector_type(4)));

constexpr int CDIM = 512;
constexpr int HID = 2048;
constexpr int MROWS = 32 * 3136;  // 100352 = 392 * 256
constexpr float LN_EPS = 1e-5f;

static __device__ __forceinline__ float gelu_tanh(float x) {
  const float u = 0.7978845608028654f * fmaf(0.044715f * x * x, x, x);
  const float e = __expf(2.0f * u);
  return 0.5f * x * (2.0f - 2.0f / (e + 1.0f));
}

// ---- transpose fp32 src[KD][ND] -> bf16 dst[ND][KD], 64x64 LDS tiles ----
template <int KD, int ND>
__global__ __launch_bounds__(256) void cvt_t(const float* __restrict__ src,
                                             __hip_bfloat16* __restrict__ dst) {
  __shared__ float tl[64][65];
  const int t = threadIdx.x;
  constexpr int NTN = ND / 64;
  const int k0 = (blockIdx.x / NTN) * 64;
  const int n0 = (blockIdx.x % NTN) * 64;
  const int c4 = (t & 15) * 4;
  const int r = t >> 4;
#pragma unroll
  for (int j = 0; j < 4; ++j) {
    const int kk = r + j * 16;
    const float4 v = *(const float4*)&src[(size_t)(k0 + kk) * ND + n0 + c4];
    tl[c4 + 0][kk] = v.x;
    tl[c4 + 1][kk] = v.y;
    tl[c4 + 2][kk] = v.z;
    tl[c4 + 3][kk] = v.w;
  }
  __syncthreads();
#pragma unroll
  for (int j = 0; j < 4; ++j) {
    const int nn = r + j * 16;
    __hip_bfloat16 o[4];
#pragma unroll
    for (int c = 0; c < 4; ++c) o[c] = __float2bfloat16(tl[nn][c4 + c]);
    *(uint2*)&dst[(size_t)(n0 + nn) * KD + k0 + c4] = *(const uint2*)o;
  }
}

// -------- fused LN1 + spatial mix + residual + LN2, 2 rows / iteration ------
__global__ __launch_bounds__(256) void fused_pre(
    const float* __restrict__ x, const float* __restrict__ g1,
    const float* __restrict__ b1, const float* __restrict__ wsp,
    const float* __restrict__ g2, const float* __restrict__ b2,
    float* __restrict__ x2out, __hip_bfloat16* __restrict__ yout) {
  __shared__ float lnbuf[2][CDIM];
  __shared__ float red[16];

  const int t = threadIdx.x;
  const int lane = t & 63;
  const int w = t >> 6;
  const int c0 = 2 * t;
  const int hd = c0 >> 5, e0 = c0 & 31;

  float wc0[32], wc1[32];
#pragma unroll
  for (int d = 0; d < 32; ++d) {
    const float2 wv = *(const float2*)&wsp[(hd * 32 + d) * 32 + e0];
    wc0[d] = wv.x;
    wc1[d] = wv.y;
  }
  const float2 g1v = *(const float2*)&g1[c0];
  const float2 b1v = *(const float2*)&b1[c0];
  const float2 g2v = *(const float2*)&g2[c0];
  const float2 b2v = *(const float2*)&b2[c0];

  for (int rp = blockIdx.x; rp < MROWS / 2; rp += gridDim.x) {
    const size_t ra = (size_t)rp * 2, rb = ra + 1;
    const float2 xa = *(const float2*)&x[ra * CDIM + c0];
    const float2 xb = *(const float2*)&x[rb * CDIM + c0];

    float sa = xa.x + xa.y, qa = xa.x * xa.x + xa.y * xa.y;
    float sb = xb.x + xb.y, qb = xb.x * xb.x + xb.y * xb.y;
#pragma unroll
    for (int off = 32; off; off >>= 1) {
      sa += __shfl_down(sa, off);
      qa += __shfl_down(qa, off);
      sb += __shfl_down(sb, off);
      qb += __shfl_down(qb, off);
    }
    if (lane == 0) {
      red[w * 4 + 0] = sa;
      red[w * 4 + 1] = qa;
      red[w * 4 + 2] = sb;
      red[w * 4 + 3] = qb;
    }
    __syncthreads();  // B1
    sa = red[0] + red[4] + red[8] + red[12];
    qa = red[1] + red[5] + red[9] + red[13];
    sb = red[2] + red[6] + red[10] + red[14];
    qb = red[3] + red[7] + red[11] + red[15];
    float mua = sa * (1.0f / CDIM), mub = sb * (1.0f / CDIM);
    float rsa = rsqrtf(qa * (1.0f / CDIM) - mua * mua + LN_EPS);
    float rsb = rsqrtf(qb * (1.0f / CDIM) - mub * mub + LN_EPS);
    lnbuf[0][c0] = (xa.x - mua) * rsa * g1v.x + b1v.x;
    lnbuf[0][c0 + 1] = (xa.y - mua) * rsa * g1v.y + b1v.y;
    lnbuf[1][c0] = (xb.x - mub) * rsb * g1v.x + b1v.x;
    lnbuf[1][c0 + 1] = (xb.y - mub) * rsb * g1v.y + b1v.y;
    __syncthreads();  // B2

    float ha0 = 0.f, ha1 = 0.f, hb0 = 0.f, hb1 = 0.f;
#pragma unroll
    for (int d = 0; d < 32; ++d) {
      const float la = lnbuf[0][hd * 32 + d];
      const float lb = lnbuf[1][hd * 32 + d];
      ha0 = fmaf(la, wc0[d], ha0);
      ha1 = fmaf(la, wc1[d], ha1);
      hb0 = fmaf(lb, wc0[d], hb0);
      hb1 = fmaf(lb, wc1[d], hb1);
    }
    const float a0 = xa.x + ha0, a1 = xa.y + ha1;
    const float b0 = xb.x + hb0, b1r = xb.y + hb1;
    float2 av;
    av.x = a0;
    av.y = a1;
    *(float2*)&x2out[ra * CDIM + c0] = av;
    av.x = b0;
    av.y = b1r;
    *(float2*)&x2out[rb * CDIM + c0] = av;

    sa = a0 + a1;
    qa = a0 * a0 + a1 * a1;
    sb = b0 + b1r;
    qb = b0 * b0 + b1r * b1r;
#pragma unroll
    for (int off = 32; off; off >>= 1) {
      sa += __shfl_down(sa, off);
      qa += __shfl_down(qa, off);
      sb += __shfl_down(sb, off);
      qb += __shfl_down(qb, off);
    }
    if (lane == 0) {
      red[w * 4 + 0] = sa;
      red[w * 4 + 1] = qa;
      red[w * 4 + 2] = sb;
      red[w * 4 + 3] = qb;
    }
    __syncthreads();  // B3
    sa = red[0] + red[4] + red[8] + red[12];
    qa = red[1] + red[5] + red[9] + red[13];
    sb = red[2] + red[6] + red[10] + red[14];
    qb = red[3] + red[7] + red[11] + red[15];
    mua = sa * (1.0f / CDIM);
    mub = sb * (1.0f / CDIM);
    rsa = rsqrtf(qa * (1.0f / CDIM) - mua * mua + LN_EPS);
    rsb = rsqrtf(qb * (1.0f / CDIM) - mub * mub + LN_EPS);
    __hip_bfloat162 yv;
    yv.x = __float2bfloat16((a0 - mua) * rsa * g2v.x + b2v.x);
    yv.y = __float2bfloat16((a1 - mua) * rsa * g2v.y + b2v.y);
    *(__hip_bfloat162*)&yout[ra * CDIM + c0] = yv;
    yv.x = __float2bfloat16((b0 - mub) * rsb * g2v.x + b2v.x);
    yv.y = __float2bfloat16((b1r - mub) * rsb * g2v.y + b2v.y);
    *(__hip_bfloat162*)&yout[rb * CDIM + c0] = yv;
    __syncthreads();  // B4
  }
}

// ---- shared epilogue: LDS bounce, full-line coalesced writes (R7-verified) --
template <int N, bool GELU>
static __device__ __forceinline__ void epilogue(const f32x4 (&acc)[8][4],
                                                char* smb, int tid, int lane,
                                                int wm, int wn, size_t am0,
                                                int bn0,
                                                const float* __restrict__ bias,
                                                __hip_bfloat16* __restrict__ zout,
                                                float* __restrict__ fout) {
  const int cr = (lane >> 4) * 4;
  const int cc = lane & 15;
  if constexpr (GELU) {
    __syncthreads();
    __hip_bfloat16* ot = (__hip_bfloat16*)smb;
#pragma unroll
    for (int n = 0; n < 4; ++n) {
      const int col = wn * 64 + n * 16 + cc;
      const float bv = bias[bn0 + col];
#pragma unroll
      for (int m = 0; m < 8; ++m) {
        const int row = wm * 128 + m * 16 + cr;
#pragma unroll
        for (int j = 0; j < 4; ++j)
          ot[(row + j) * 256 + col] =
              __float2bfloat16(gelu_tanh(acc[m][n][j] + bv));
      }
    }
    __syncthreads();
#pragma unroll
    for (int it = 0; it < 16; ++it) {
      const int seg = it * 512 + tid;
      const int row = seg >> 5, cs = seg & 31;
      const uint4 v = *(const uint4*)(smb + seg * 16);
      *(uint4*)&zout[(am0 + row) * N + bn0 + cs * 8] = v;
    }
  } else {
    float* ot = (float*)smb;
#pragma unroll
    for (int p = 0; p < 2; ++p) {
      __syncthreads();
      if (wm == p) {
#pragma unroll
        for (int n = 0; n < 4; ++n) {
          const int col = wn * 64 + n * 16 + cc;
          const float bv = bias[bn0 + col];
#pragma unroll
          for (int m = 0; m < 8; ++m) {
            const int rl = m * 16 + cr;
#pragma unroll
            for (int j = 0; j < 4; ++j)
              ot[(rl + j) * 256 + col] = acc[m][n][j] + bv;
          }
        }
      }
      __syncthreads();
#pragma unroll
      for (int it = 0; it < 16; ++it) {
        const int seg = it * 512 + tid;
        const int row = seg >> 6, cs = seg & 63;
        const float4 lv = *(const float4*)(smb + seg * 16);
        float* gp = &fout[(am0 + p * 128 + row) * N + bn0 + cs * 4];
        float4 o = *(const float4*)gp;
        o.x += lv.x;
        o.y += lv.y;
        o.z += lv.z;
        o.w += lv.w;
        *(float4*)gp = o;
      }
    }
  }
}

// ---- 8-wave 256x256, direct global->VGPR fragments, ZERO K-loop sync ----
// C(MxN) = A(MxK) * Bt(NxK)^T. Per-lane addressing identical to the LDS
// fragment reads (row = base+fr, 16B at kg*16): 16-line gather per load,
// lines fully consumed by the 4 kg-lanes; A/B panels L1/L2-resident.
// LDS (128KB) touched only by the epilogue bounce.
template <int K, int N, bool GELU>
__global__ __launch_bounds__(512) void gemmdr(
    const __hip_bfloat16* __restrict__ A, const __hip_bfloat16* __restrict__ Bt,
    const float* __restrict__ bias, __hip_bfloat16* __restrict__ zout,
    float* __restrict__ fout) {
  constexpr int NT = N / 256;
  constexpr int NKT = K / 32;
  __shared__ __attribute__((aligned(16))) __hip_bfloat16 lds[256 * 256];

  const int tid = threadIdx.x;
  const int lane = tid & 63;
  const int w = tid >> 6;
  const int wm = w >> 2, wn = w & 3;  // wave tile 128x64 (2M x 4N)

  // T1: XCD-aware bijective swizzle (grid % 8 == 0 by construction)
  const int cpx = gridDim.x >> 3;
  const int bid = (blockIdx.x & 7) * cpx + (blockIdx.x >> 3);
  const int tm = bid / NT, tn = bid - tm * NT;
  const size_t am0 = (size_t)tm * 256;
  const int bn0 = tn * 256;

  const int fr = lane & 15;
  const int kg = lane >> 4;

  const __hip_bfloat16* aR = A + (am0 + wm * 128 + fr) * K + kg * 8;
  const __hip_bfloat16* bR = Bt + (size_t)(bn0 + wn * 64 + fr) * K + kg * 8;

  f32x4 acc[8][4] = {};

#pragma unroll 4
  for (int t = 0; t < NKT; ++t) {
    const int kof = t * 32;
    bf16x8 af[8], bf[4];
#pragma unroll
    for (int m = 0; m < 8; ++m)
      af[m] = *(const bf16x8*)(aR + (size_t)(m * 16) * K + kof);
#pragma unroll
    for (int n = 0; n < 4; ++n)
      bf[n] = *(const bf16x8*)(bR + (size_t)(n * 16) * K + kof);
#pragma unroll
    for (int m = 0; m < 8; ++m)
#pragma unroll
      for (int n = 0; n < 4; ++n)
        acc[m][n] = __builtin_amdgcn_mfma_f32_16x16x32_bf16(af[m], bf[n],
                                                            acc[m][n], 0, 0, 0);
  }

  epilogue<N, GELU>(acc, (char*)lds, tid, lane, wm, wn, am0, bn0, bias, zout,
                    fout);
}

extern "C" void kernel_launch(void* const* d_in, const int* in_sizes, int n_in,
                              void* d_out, int out_size, void* d_ws,
                              size_t ws_size, hipStream_t stream) {
  const float* x = (const float*)d_in[0];
  const float* n1g = (const float*)d_in[1];
  const float* n1b = (const float*)d_in[2];
  const float* wsp = (const float*)d_in[3];
  const float* n2g = (const float*)d_in[4];
  const float* n2b = (const float*)d_in[5];
  const float* w1 = (const float*)d_in[6];
  const float* b1 = (const float*)d_in[7];
  const float* w2 = (const float*)d_in[8];
  const float* b2 = (const float*)d_in[9];
  float* out = (float*)d_out;

  __hip_bfloat16* ybuf = (__hip_bfloat16*)d_ws;
  __hip_bfloat16* zbuf = ybuf + (size_t)MROWS * CDIM;
  __hip_bfloat16* w1t = zbuf + (size_t)MROWS * HID;
  __hip_bfloat16* w2t = w1t + (size_t)CDIM * HID;

  cvt_t<CDIM, HID><<<(CDIM / 64) * (HID / 64), 256, 0, stream>>>(w1, w1t);
  cvt_t<HID, CDIM><<<(HID / 64) * (CDIM / 64), 256, 0, stream>>>(w2, w2t);
  fused_pre<<<2048, 256, 0, stream>>>(x, n1g, n1b, wsp, n2g, n2b, out, ybuf);
  // grids: 392*8 = 3136 and 392*2 = 784, both % 8 == 0
  gemmdr<CDIM, HID, true><<<(MROWS / 256) * (HID / 256), 512, 0, stream>>>(
      ybuf, w1t, b1, zbuf, nullptr);
  gemmdr<HID, CDIM, false><<<(MROWS / 256) * (CDIM / 256), 512, 0, stream>>>(
      zbuf, w2t, b2, nullptr, out);
}

// Round 12
// 867.767 us; speedup vs baseline: 2.1298x; 2.1298x over previous
//
#include <hip/hip_runtime.h>
#include <hip/hip_bf16.h>

// SwinMLP block, fp32 in/out, bf16 MFMA internals.
//   1) cvt_t: w1 -> w1t (bf16, NxK), w2 -> w2t (bf16, NxK)
//   2) fused_pre: LN1 + per-head 32x32 spatial mix + residual -> x2 (d_out)
//      + LN2(x2) -> y (bf16, ws)
//   3) gemm97<512,2048,GELU>: z = gelu(y @ w1 + b1)
//   4) gemm97<2048,512,RES>:  d_out = x2 + z @ w2 + b2
//
// Session model (R1-R10): operand delivery MUST be LDS (R10: direct global
// gather = 9.7% MfmaUtil). 256²/8-wave variants = 1 reg-bound block/CU ->
// barrier-lockstep, no foreign waves; schedule variants null (~22% MfmaUtil).
// R11 tested 3 independent blocks/CU via __launch_bounds__(256,3) but had an
// LDS OVERFLOW: 16KB staging buffer, 32KB epilogue bounce -> OOB writes,
// absmax 3.74. R12 (this): identical experiment, LDS sized correctly at
// 32KB (staging uses first 16KB; bounce uses all 32KB). 3x32KB=96KB<160KB,
// so the register cap (<=170 unified incl 64 AGPR acc) is what's tested.

typedef __bf16 bf16x8 __attribute__((ext_vector_type(8)));
typedef float f32x4 __attribute__((ext_vector_type(4)));

constexpr int CDIM = 512;
constexpr int HID = 2048;
constexpr int MROWS = 32 * 3136;  // 100352 = 784 * 128
constexpr float LN_EPS = 1e-5f;

static __device__ __forceinline__ float gelu_tanh(float x) {
  const float u = 0.7978845608028654f * fmaf(0.044715f * x * x, x, x);
  const float e = __expf(2.0f * u);
  return 0.5f * x * (2.0f - 2.0f / (e + 1.0f));
}

static __device__ __forceinline__ void load_lds16(const void* g, void* l) {
  // 16B/lane; LDS dest = wave-uniform base + lane*16 (linear)
  __builtin_amdgcn_global_load_lds((__attribute__((address_space(1))) void*)g,
                                   (__attribute__((address_space(3))) void*)l,
                                   16, 0, 0);
}

// ---- transpose fp32 src[KD][ND] -> bf16 dst[ND][KD], 64x64 LDS tiles ----
template <int KD, int ND>
__global__ __launch_bounds__(256) void cvt_t(const float* __restrict__ src,
                                             __hip_bfloat16* __restrict__ dst) {
  __shared__ float tl[64][65];
  const int t = threadIdx.x;
  constexpr int NTN = ND / 64;
  const int k0 = (blockIdx.x / NTN) * 64;
  const int n0 = (blockIdx.x % NTN) * 64;
  const int c4 = (t & 15) * 4;
  const int r = t >> 4;
#pragma unroll
  for (int j = 0; j < 4; ++j) {
    const int kk = r + j * 16;
    const float4 v = *(const float4*)&src[(size_t)(k0 + kk) * ND + n0 + c4];
    tl[c4 + 0][kk] = v.x;
    tl[c4 + 1][kk] = v.y;
    tl[c4 + 2][kk] = v.z;
    tl[c4 + 3][kk] = v.w;
  }
  __syncthreads();
#pragma unroll
  for (int j = 0; j < 4; ++j) {
    const int nn = r + j * 16;
    __hip_bfloat16 o[4];
#pragma unroll
    for (int c = 0; c < 4; ++c) o[c] = __float2bfloat16(tl[nn][c4 + c]);
    *(uint2*)&dst[(size_t)(n0 + nn) * KD + k0 + c4] = *(const uint2*)o;
  }
}

// -------- fused LN1 + spatial mix + residual + LN2, 2 rows / iteration ------
__global__ __launch_bounds__(256) void fused_pre(
    const float* __restrict__ x, const float* __restrict__ g1,
    const float* __restrict__ b1, const float* __restrict__ wsp,
    const float* __restrict__ g2, const float* __restrict__ b2,
    float* __restrict__ x2out, __hip_bfloat16* __restrict__ yout) {
  __shared__ float lnbuf[2][CDIM];
  __shared__ float red[16];

  const int t = threadIdx.x;
  const int lane = t & 63;
  const int w = t >> 6;
  const int c0 = 2 * t;
  const int hd = c0 >> 5, e0 = c0 & 31;

  float wc0[32], wc1[32];
#pragma unroll
  for (int d = 0; d < 32; ++d) {
    const float2 wv = *(const float2*)&wsp[(hd * 32 + d) * 32 + e0];
    wc0[d] = wv.x;
    wc1[d] = wv.y;
  }
  const float2 g1v = *(const float2*)&g1[c0];
  const float2 b1v = *(const float2*)&b1[c0];
  const float2 g2v = *(const float2*)&g2[c0];
  const float2 b2v = *(const float2*)&b2[c0];

  for (int rp = blockIdx.x; rp < MROWS / 2; rp += gridDim.x) {
    const size_t ra = (size_t)rp * 2, rb = ra + 1;
    const float2 xa = *(const float2*)&x[ra * CDIM + c0];
    const float2 xb = *(const float2*)&x[rb * CDIM + c0];

    float sa = xa.x + xa.y, qa = xa.x * xa.x + xa.y * xa.y;
    float sb = xb.x + xb.y, qb = xb.x * xb.x + xb.y * xb.y;
#pragma unroll
    for (int off = 32; off; off >>= 1) {
      sa += __shfl_down(sa, off);
      qa += __shfl_down(qa, off);
      sb += __shfl_down(sb, off);
      qb += __shfl_down(qb, off);
    }
    if (lane == 0) {
      red[w * 4 + 0] = sa;
      red[w * 4 + 1] = qa;
      red[w * 4 + 2] = sb;
      red[w * 4 + 3] = qb;
    }
    __syncthreads();  // B1
    sa = red[0] + red[4] + red[8] + red[12];
    qa = red[1] + red[5] + red[9] + red[13];
    sb = red[2] + red[6] + red[10] + red[14];
    qb = red[3] + red[7] + red[11] + red[15];
    float mua = sa * (1.0f / CDIM), mub = sb * (1.0f / CDIM);
    float rsa = rsqrtf(qa * (1.0f / CDIM) - mua * mua + LN_EPS);
    float rsb = rsqrtf(qb * (1.0f / CDIM) - mub * mub + LN_EPS);
    lnbuf[0][c0] = (xa.x - mua) * rsa * g1v.x + b1v.x;
    lnbuf[0][c0 + 1] = (xa.y - mua) * rsa * g1v.y + b1v.y;
    lnbuf[1][c0] = (xb.x - mub) * rsb * g1v.x + b1v.x;
    lnbuf[1][c0 + 1] = (xb.y - mub) * rsb * g1v.y + b1v.y;
    __syncthreads();  // B2

    float ha0 = 0.f, ha1 = 0.f, hb0 = 0.f, hb1 = 0.f;
#pragma unroll
    for (int d = 0; d < 32; ++d) {
      const float la = lnbuf[0][hd * 32 + d];
      const float lb = lnbuf[1][hd * 32 + d];
      ha0 = fmaf(la, wc0[d], ha0);
      ha1 = fmaf(la, wc1[d], ha1);
      hb0 = fmaf(lb, wc0[d], hb0);
      hb1 = fmaf(lb, wc1[d], hb1);
    }
    const float a0 = xa.x + ha0, a1 = xa.y + ha1;
    const float b0 = xb.x + hb0, b1r = xb.y + hb1;
    float2 av;
    av.x = a0;
    av.y = a1;
    *(float2*)&x2out[ra * CDIM + c0] = av;
    av.x = b0;
    av.y = b1r;
    *(float2*)&x2out[rb * CDIM + c0] = av;

    sa = a0 + a1;
    qa = a0 * a0 + a1 * a1;
    sb = b0 + b1r;
    qb = b0 * b0 + b1r * b1r;
#pragma unroll
    for (int off = 32; off; off >>= 1) {
      sa += __shfl_down(sa, off);
      qa += __shfl_down(qa, off);
      sb += __shfl_down(sb, off);
      qb += __shfl_down(qb, off);
    }
    if (lane == 0) {
      red[w * 4 + 0] = sa;
      red[w * 4 + 1] = qa;
      red[w * 4 + 2] = sb;
      red[w * 4 + 3] = qb;
    }
    __syncthreads();  // B3
    sa = red[0] + red[4] + red[8] + red[12];
    qa = red[1] + red[5] + red[9] + red[13];
    sb = red[2] + red[6] + red[10] + red[14];
    qb = red[3] + red[7] + red[11] + red[15];
    mua = sa * (1.0f / CDIM);
    mub = sb * (1.0f / CDIM);
    rsa = rsqrtf(qa * (1.0f / CDIM) - mua * mua + LN_EPS);
    rsb = rsqrtf(qb * (1.0f / CDIM) - mub * mub + LN_EPS);
    __hip_bfloat162 yv;
    yv.x = __float2bfloat16((a0 - mua) * rsa * g2v.x + b2v.x);
    yv.y = __float2bfloat16((a1 - mua) * rsa * g2v.y + b2v.y);
    *(__hip_bfloat162*)&yout[ra * CDIM + c0] = yv;
    yv.x = __float2bfloat16((b0 - mub) * rsb * g2v.x + b2v.x);
    yv.y = __float2bfloat16((b1r - mub) * rsb * g2v.y + b2v.y);
    *(__hip_bfloat162*)&yout[rb * CDIM + c0] = yv;
    __syncthreads();  // B4
  }
}

// ---- m97-structure GEMM: 128x128 tile, 4 waves (2x2 of 64x64), BK=32 ----
// C(MxN) = A(MxK) * Bt(NxK)^T.  LDS block = 32KB: staging As(8KB)+Bs(8KB)
// in the first half; epilogue bounce uses all 32KB (R11 bug: it was 16KB).
// K-step: {4x global_load_lds; barrier; 8x ds_read_b128; 16 MFMA; barrier}.
// __launch_bounds__(256,3): forces <=170 unified regs -> 3 blocks/CU; three
// independent 4-wave barrier groups overlap each other's drains (m114).
template <int K, int N, bool GELU>
__global__ __launch_bounds__(256, 3) void gemm97(
    const __hip_bfloat16* __restrict__ A, const __hip_bfloat16* __restrict__ Bt,
    const float* __restrict__ bias, __hip_bfloat16* __restrict__ zout,
    float* __restrict__ fout) {
  constexpr int NT = N / 128;
  constexpr int NKT = K / 32;
  __shared__ __attribute__((aligned(16))) char smem_raw[32768];
  __hip_bfloat16* Asm = (__hip_bfloat16*)smem_raw;           // 8KB staging A
  __hip_bfloat16* Bsm = (__hip_bfloat16*)(smem_raw + 8192);  // 8KB staging B

  const int tid = threadIdx.x;
  const int lane = tid & 63;
  const int w = tid >> 6;             // 0..3
  const int wr = w >> 1, wc = w & 1;  // wave tile 64x64

  // T1: XCD-aware bijective swizzle (grid % 8 == 0 by construction)
  const int cpx = gridDim.x >> 3;
  const int bid = (blockIdx.x & 7) * cpx + (blockIdx.x >> 3);
  const int tm = bid / NT, tn = bid - tm * NT;
  const size_t am0 = (size_t)tm * 128;
  const int bn0 = tn * 128;

  // staging: thread t stages segs t (rows 0..63) and t+256 (rows 64..127)
  const int r0 = tid >> 2, q0 = tid & 3;
  const __hip_bfloat16* aP0 = A + (am0 + r0) * K + q0 * 8;
  const __hip_bfloat16* aP1 = aP0 + (size_t)64 * K;
  const __hip_bfloat16* bP0 = Bt + (size_t)(bn0 + r0) * K + q0 * 8;
  const __hip_bfloat16* bP1 = bP0 + (size_t)64 * K;
  const int lo0 = (w * 64) * 8;          // wave-uniform LDS elem offset
  const int lo1 = (256 + w * 64) * 8;

  // fragment geometry: row = base + fr; byte = row*64 + kg*16
  const int fr = lane & 15;
  const int kb = (lane >> 4) * 16;

  f32x4 acc[4][4] = {};

  for (int t = 0; t < NKT; ++t) {
    const int kof = t * 32;
    load_lds16(aP0 + kof, &Asm[lo0]);
    load_lds16(aP1 + kof, &Asm[lo1]);
    load_lds16(bP0 + kof, &Bsm[lo0]);
    load_lds16(bP1 + kof, &Bsm[lo1]);
    __syncthreads();  // compiler-inserted vmcnt(0) drain + barrier

    bf16x8 af[4], bf[4];
#pragma unroll
    for (int m = 0; m < 4; ++m)
      af[m] = *(const bf16x8*)((const char*)Asm +
                               (wr * 64 + m * 16 + fr) * 64 + kb);
#pragma unroll
    for (int n = 0; n < 4; ++n)
      bf[n] = *(const bf16x8*)((const char*)Bsm +
                               (wc * 64 + n * 16 + fr) * 64 + kb);
#pragma unroll
    for (int m = 0; m < 4; ++m)
#pragma unroll
      for (int n = 0; n < 4; ++n)
        acc[m][n] = __builtin_amdgcn_mfma_f32_16x16x32_bf16(af[m], bf[n],
                                                            acc[m][n], 0, 0, 0);
    __syncthreads();  // LDS reads done before next stage overwrites
  }

  // ---- epilogue via 32KB LDS bounce ----
  // C/D map: col = lane&15, row = (lane>>4)*4 + j  [m89/m91-verified]
  const int cr = (lane >> 4) * 4;
  const int cc = lane & 15;
  char* smb = smem_raw;

  if constexpr (GELU) {
    // bf16 out: 128x128 bf16 = exactly 32KB
    __hip_bfloat16* ot = (__hip_bfloat16*)smb;
#pragma unroll
    for (int n = 0; n < 4; ++n) {
      const int col = wc * 64 + n * 16 + cc;
      const float bv = bias[bn0 + col];
#pragma unroll
      for (int m = 0; m < 4; ++m) {
        const int row = wr * 64 + m * 16 + cr;
#pragma unroll
        for (int j = 0; j < 4; ++j)
          ot[(row + j) * 128 + col] =
              __float2bfloat16(gelu_tanh(acc[m][n][j] + bv));
      }
    }
    __syncthreads();
#pragma unroll
    for (int it = 0; it < 8; ++it) {
      const int seg = it * 256 + tid;  // 2048 x 16B = 32KB
      const int row = seg >> 4, cs = seg & 15;
      const uint4 v = *(const uint4*)(smb + seg * 16);
      *(uint4*)&zout[(am0 + row) * N + bn0 + cs * 8] = v;
    }
  } else {
    // fp32 RMW out: 2 passes of 64 rows (64x128 f32 = 32KB)
    float* ot = (float*)smb;
#pragma unroll
    for (int p = 0; p < 2; ++p) {
      __syncthreads();
      if (wr == p) {
#pragma unroll
        for (int n = 0; n < 4; ++n) {
          const int col = wc * 64 + n * 16 + cc;
          const float bv = bias[bn0 + col];
#pragma unroll
          for (int m = 0; m < 4; ++m) {
            const int rl = m * 16 + cr;
#pragma unroll
            for (int j = 0; j < 4; ++j)
              ot[(rl + j) * 128 + col] = acc[m][n][j] + bv;
          }
        }
      }
      __syncthreads();
#pragma unroll
      for (int it = 0; it < 8; ++it) {
        const int seg = it * 256 + tid;  // 2048 x 16B = 32KB
        const int row = seg >> 5, cs = seg & 31;
        const float4 lv = *(const float4*)(smb + seg * 16);
        float* gp = &fout[(am0 + p * 64 + row) * N + bn0 + cs * 4];
        float4 o = *(const float4*)gp;
        o.x += lv.x;
        o.y += lv.y;
        o.z += lv.z;
        o.w += lv.w;
        *(float4*)gp = o;
      }
    }
  }
}

extern "C" void kernel_launch(void* const* d_in, const int* in_sizes, int n_in,
                              void* d_out, int out_size, void* d_ws,
                              size_t ws_size, hipStream_t stream) {
  const float* x = (const float*)d_in[0];
  const float* n1g = (const float*)d_in[1];
  const float* n1b = (const float*)d_in[2];
  const float* wsp = (const float*)d_in[3];
  const float* n2g = (const float*)d_in[4];
  const float* n2b = (const float*)d_in[5];
  const float* w1 = (const float*)d_in[6];
  const float* b1 = (const float*)d_in[7];
  const float* w2 = (const float*)d_in[8];
  const float* b2 = (const float*)d_in[9];
  float* out = (float*)d_out;

  __hip_bfloat16* ybuf = (__hip_bfloat16*)d_ws;
  __hip_bfloat16* zbuf = ybuf + (size_t)MROWS * CDIM;
  __hip_bfloat16* w1t = zbuf + (size_t)MROWS * HID;
  __hip_bfloat16* w2t = w1t + (size_t)CDIM * HID;

  cvt_t<CDIM, HID><<<(CDIM / 64) * (HID / 64), 256, 0, stream>>>(w1, w1t);
  cvt_t<HID, CDIM><<<(HID / 64) * (CDIM / 64), 256, 0, stream>>>(w2, w2t);
  fused_pre<<<2048, 256, 0, stream>>>(x, n1g, n1b, wsp, n2g, n2b, out, ybuf);
  // grids: 784*16 = 12544 and 784*4 = 3136, both % 8 == 0
  gemm97<CDIM, HID, true><<<(MROWS / 128) * (HID / 128), 256, 0, stream>>>(
      ybuf, w1t, b1, zbuf, nullptr);
  gemm97<HID, CDIM, false><<<(MROWS / 128) * (CDIM / 128), 256, 0, stream>>>(
      zbuf, w2t, b2, nullptr, out);
}